// Round 6
// baseline (302.781 us; speedup 1.0000x reference)
//
#include <hip/hip_runtime.h>

typedef unsigned short ushort_t;
typedef unsigned int uint_t;

using bf16x8 = __attribute__((ext_vector_type(8))) short;
using f32x4  = __attribute__((ext_vector_type(4))) float;

// ---------- helpers ----------
__device__ __forceinline__ ushort_t f2b(float f){
    union { float f; uint_t u; } v; v.f = f;
    uint_t u = v.u;
    uint_t r = (u + 0x7FFFu + ((u >> 16) & 1u)) >> 16;   // RNE
    return (ushort_t)r;
}
__device__ __forceinline__ float b2f(ushort_t u){
    union { uint_t u; float f; } v; v.u = ((uint_t)u) << 16; return v.f;
}

// ---------- weight prep: f32 -> bf16 (+ conv restride) ----------
__global__ void prep_k(const float* __restrict__ vW, const float* __restrict__ Wx,
                       const float* __restrict__ Wh, const float* __restrict__ cW,
                       const float* __restrict__ sW, const float* __restrict__ oW,
                       const float* __restrict__ pW, ushort_t* __restrict__ wb)
{
    int idx = blockIdx.x * 256 + threadIdx.x;
    switch (blockIdx.y){
    case 0: if (idx < 16384) wb[idx]          = f2b(vW[idx]);           break;
    case 1: if (idx < 65536) wb[16384  + idx] = f2b(Wx[idx]);           break; // Wx0
    case 2: if (idx < 65536) wb[81920  + idx] = f2b(Wh[idx]);           break; // Wh0
    case 3: if (idx < 65536) wb[147456 + idx] = f2b(Wx[65536 + idx]);   break; // Wx1
    case 4: if (idx < 65536) wb[212992 + idx] = f2b(Wh[65536 + idx]);   break; // Wh1
    case 5: if (idx < 49152){                                                  // conv [k][o][i]
                int k = idx >> 14; int oi = idx & 16383;
                wb[278528 + idx] = f2b(cW[oi * 3 + k]);
            } break;
    case 6: if (idx < 16384) wb[327680 + idx] = f2b(sW[idx]);           break;
    case 7: if (idx < 16384) wb[344064 + idx] = f2b(oW[idx]);           break;
    case 8: if (idx < 12288) wb[360448 + idx] = f2b(pW[idx]);           break;
    }
}

// ---------- patch embed + layernorm ----------
__global__ void embed_ln_k(const float* __restrict__ x, const float* __restrict__ eW,
                           const float* __restrict__ eb, const float* __restrict__ lng,
                           const float* __restrict__ lnb,
                           float* __restrict__ xnF, ushort_t* __restrict__ xnB)
{
    const int e  = threadIdx.x;
    const int bc = blockIdx.x;
    const int b  = bc / 21, c = bc % 21;
    const int wid = threadIdx.x >> 6;

    float w[16];
#pragma unroll
    for (int p = 0; p < 16; ++p) w[p] = eW[e * 16 + p];
    const float bias = eb[e], gam = lng[e], bet = lnb[e];

    __shared__ float patch[16];
    __shared__ float red[4];

    for (int n = 0; n < 8; ++n){
        if (e < 16) patch[e] = x[(b * 128 + n * 16 + e) * 21 + c];
        __syncthreads();
        float v = bias;
#pragma unroll
        for (int p = 0; p < 16; ++p) v += w[p] * patch[p];

        float s = v, sq = v * v;
#pragma unroll
        for (int m = 32; m >= 1; m >>= 1){
            s  += __shfl_xor(s,  m);
            sq += __shfl_xor(sq, m);
        }
        if ((threadIdx.x & 63) == 0){ red[wid] = s; red[2 + wid] = sq; }
        __syncthreads();
        float S  = red[0] + red[1];
        float SQ = red[2] + red[3];
        float mean = S * (1.f / 128.f);
        float var  = SQ * (1.f / 128.f) - mean * mean;
        float r    = rsqrtf(var + 1e-5f);
        float y    = (v - mean) * r * gam + bet;
        int row = bc * 8 + n;
        xnF[row * 128 + e] = y;
        xnB[row * 128 + e] = f2b(y);
        __syncthreads();
    }
}

// ---------- generic MFMA matmul: Y(ROWSx OUT) = A(ROWSx128) @ W(OUTx128)^T + bias ----------
__global__ void mm16_k(const ushort_t* __restrict__ A, const ushort_t* __restrict__ W,
                       const float* __restrict__ bias, const float* __restrict__ resid,
                       float* __restrict__ outF, ushort_t* __restrict__ outB, int OUT)
{
    const int lane = threadIdx.x & 63, wave = threadIdx.x >> 6;
    const int rowbase = blockIdx.x * 64 + wave * 16;
    const int r0 = lane & 15, g = lane >> 4;

    bf16x8 a[4];
    const ushort_t* ap = A + (rowbase + r0) * 128 + g * 8;
#pragma unroll
    for (int kt = 0; kt < 4; ++kt) a[kt] = *(const bf16x8*)(ap + kt * 32);

    const int ntiles = OUT >> 4;
    for (int nt = 0; nt < ntiles; ++nt){
        const int col = nt * 16 + r0;
        float bv = bias[col];
        f32x4 acc = {bv, bv, bv, bv};
        const ushort_t* wp = W + col * 128 + g * 8;
#pragma unroll
        for (int kt = 0; kt < 4; ++kt)
            acc = __builtin_amdgcn_mfma_f32_16x16x32_bf16(a[kt], *(const bf16x8*)(wp + kt * 32), acc, 0, 0, 0);
#pragma unroll
        for (int q = 0; q < 4; ++q){
            int row = rowbase + g * 4 + q;
            float val = acc[q];
            if (resid) val += resid[row * 128 + col];
            if (outF)  outF[row * OUT + col] = val;
            if (outB)  outB[row * OUT + col] = f2b(val);
        }
    }
}

// ---------- LSTM layer 0: independent 64-step recurrence ----------
// grid 42, block 512 (8 waves). 16 batch rows/block. Only Wh0 in registers (64).
// Phase: 4 ds_reads + 16 MFMA + EW + h0 LDS/global store + X0 prefetch.
__global__ __launch_bounds__(512) void lstm0_k(
    const float* __restrict__ X0, const ushort_t* __restrict__ Wh0,
    ushort_t* __restrict__ h0g)
{
    __shared__ ushort_t h0[2][2048];
    const int tid = threadIdx.x;
    const int wid = tid >> 6, lane = tid & 63;
    const int r0 = lane & 15, g = lane >> 4;
    const int sw = r0 & 7;
    const int bcb = blockIdx.x * 16;
    const float K1 = 1.44269504f, K2 = 2.88539008f;

    for (int i = tid; i < 4096; i += 512) ((ushort_t*)h0)[i] = 0;

    bf16x8 wh0[4][4];
#pragma unroll
    for (int t4 = 0; t4 < 4; ++t4){
        const int cb = t4 * 128 + wid * 16;
#pragma unroll
        for (int kt = 0; kt < 4; ++kt)
            wh0[t4][kt] = *(const bf16x8*)(Wh0 + (cb + r0) * 128 + kt * 32 + g * 8);
    }

    float c0[4] = {0,0,0,0};
    f32x4 acc[4];
#pragma unroll
    for (int t4 = 0; t4 < 4; ++t4)
#pragma unroll
        for (int q = 0; q < 4; ++q)
            acc[t4][q] = X0[(bcb + g * 4 + q) * 4096 + t4 * 128 + wid * 16 + r0];

    __syncthreads();

    for (int t = 0; t < 64; ++t){
        const int p = t & 1;
        bf16x8 a0[4];
#pragma unroll
        for (int kt = 0; kt < 4; ++kt)
            a0[kt] = *(const bf16x8*)(&h0[p][r0 * 128 + ((kt * 32 + g * 8) ^ (sw << 3))]);
#pragma unroll
        for (int kt = 0; kt < 4; ++kt)
#pragma unroll
            for (int t4 = 0; t4 < 4; ++t4)
                acc[t4] = __builtin_amdgcn_mfma_f32_16x16x32_bf16(a0[kt], wh0[t4][kt], acc[t4], 0, 0, 0);
#pragma unroll
        for (int q = 0; q < 4; ++q){
            float iv = acc[0][q], fv = acc[1][q], gv = acc[2][q], ov = acc[3][q];
            float af = 1.f + __builtin_amdgcn_exp2f(-K1 * fv);
            float ai = 1.f + __builtin_amdgcn_exp2f(-K1 * iv);
            float bg = 1.f + __builtin_amdgcn_exp2f( K2 * gv);
            float cn = c0[q] * __builtin_amdgcn_rcpf(af)
                     + (bg - 2.f) * __builtin_amdgcn_rcpf(ai * bg);
            c0[q] = cn;
            float ao = 1.f + __builtin_amdgcn_exp2f(-K1 * ov);
            float bc = 1.f + __builtin_amdgcn_exp2f( K2 * cn);
            float hv = (bc - 2.f) * __builtin_amdgcn_rcpf(ao * bc);
            int row = g * 4 + q;
            ushort_t hb = f2b(hv);
            h0[p ^ 1][row * 128 + ((wid * 16 + r0) ^ ((row & 7) << 3))] = hb;
            h0g[((bcb + row) * 64 + t) * 128 + wid * 16 + r0] = hb;
        }
        if (t < 63){
            const int tn = (t + 1) & 7;
#pragma unroll
            for (int t4 = 0; t4 < 4; ++t4)
#pragma unroll
                for (int q = 0; q < 4; ++q)
                    acc[t4][q] = X0[(bcb + g * 4 + q) * 4096 + tn * 512 + t4 * 128 + wid * 16 + r0];
        }
        __syncthreads();
    }
}

// ---------- LSTM layer 1: 64-step recurrence consuming X1 = Wx1@h0 + b1 ----------
// grid 42, block 512. Only Wh1 in registers (64). X1 prefetched one step ahead.
__global__ __launch_bounds__(512) void lstm1_k(
    const ushort_t* __restrict__ X1, const ushort_t* __restrict__ Wh1,
    ushort_t* __restrict__ outB)
{
    __shared__ ushort_t h1[2][2048];
    const int tid = threadIdx.x;
    const int wid = tid >> 6, lane = tid & 63;
    const int r0 = lane & 15, g = lane >> 4;
    const int sw = r0 & 7;
    const int bcb = blockIdx.x * 16;
    const float K1 = 1.44269504f, K2 = 2.88539008f;

    for (int i = tid; i < 4096; i += 512) ((ushort_t*)h1)[i] = 0;

    bf16x8 wh1[4][4];
#pragma unroll
    for (int t4 = 0; t4 < 4; ++t4){
        const int cb = t4 * 128 + wid * 16;
#pragma unroll
        for (int kt = 0; kt < 4; ++kt)
            wh1[t4][kt] = *(const bf16x8*)(Wh1 + (cb + r0) * 128 + kt * 32 + g * 8);
    }

    float c1[4] = {0,0,0,0};
    f32x4 acc[4];
#pragma unroll
    for (int t4 = 0; t4 < 4; ++t4)
#pragma unroll
        for (int q = 0; q < 4; ++q)
            acc[t4][q] = b2f(X1[((bcb + g * 4 + q) * 64 + 0) * 512 + t4 * 128 + wid * 16 + r0]);

    __syncthreads();

    for (int t = 0; t < 64; ++t){
        const int p = t & 1;
        bf16x8 ah[4];
#pragma unroll
        for (int kt = 0; kt < 4; ++kt)
            ah[kt] = *(const bf16x8*)(&h1[p][r0 * 128 + ((kt * 32 + g * 8) ^ (sw << 3))]);
#pragma unroll
        for (int kt = 0; kt < 4; ++kt)
#pragma unroll
            for (int t4 = 0; t4 < 4; ++t4)
                acc[t4] = __builtin_amdgcn_mfma_f32_16x16x32_bf16(ah[kt], wh1[t4][kt], acc[t4], 0, 0, 0);
#pragma unroll
        for (int q = 0; q < 4; ++q){
            float iv = acc[0][q], fv = acc[1][q], gv = acc[2][q], ov = acc[3][q];
            float af = 1.f + __builtin_amdgcn_exp2f(-K1 * fv);
            float ai = 1.f + __builtin_amdgcn_exp2f(-K1 * iv);
            float bg = 1.f + __builtin_amdgcn_exp2f( K2 * gv);
            float cn = c1[q] * __builtin_amdgcn_rcpf(af)
                     + (bg - 2.f) * __builtin_amdgcn_rcpf(ai * bg);
            c1[q] = cn;
            float ao = 1.f + __builtin_amdgcn_exp2f(-K1 * ov);
            float bc = 1.f + __builtin_amdgcn_exp2f( K2 * cn);
            float hv = (bc - 2.f) * __builtin_amdgcn_rcpf(ao * bc);
            int row = g * 4 + q;
            ushort_t hb = f2b(hv);
            h1[p ^ 1][row * 128 + ((wid * 16 + r0) ^ ((row & 7) << 3))] = hb;
            if (t >= 56)
                outB[((bcb + row) * 8 + (t & 7)) * 128 + wid * 16 + r0] = hb;
        }
        if (t < 63){
#pragma unroll
            for (int t4 = 0; t4 < 4; ++t4)
#pragma unroll
                for (int q = 0; q < 4; ++q)
                    acc[t4][q] = b2f(X1[((bcb + g * 4 + q) * 64 + t + 1) * 512 + t4 * 128 + wid * 16 + r0]);
        }
        __syncthreads();
    }
}

// ---------- fused tail: conv1d(SAME,K=3) -> ssm -> outp(+resid xn) -> proj ----------
__global__ __launch_bounds__(256) void tail_k(
    const ushort_t* __restrict__ ls, const ushort_t* __restrict__ cWk,
    const float* __restrict__ cbias, const ushort_t* __restrict__ sW,
    const float* __restrict__ sbias, const ushort_t* __restrict__ oW,
    const float* __restrict__ obias, const float* __restrict__ xnF,
    const ushort_t* __restrict__ pW, const float* __restrict__ pbias,
    float* __restrict__ out)
{
    __shared__ ushort_t bufA[8192];
    __shared__ ushort_t bufB[8192];
    const int lane = threadIdx.x & 63, wave = threadIdx.x >> 6;
    const int r0 = lane & 15, g = lane >> 4;
    const int rowbase = blockIdx.x * 64;
    const int lr0 = wave * 16;

    // ---- conv ----
    {
        const int n = r0 & 7;
        bf16x8 a[3][4];
#pragma unroll
        for (int k = 0; k < 3; ++k){
            bool valid = (n + k >= 1) && (n + k <= 8);
            const ushort_t* ap = ls + (rowbase + lr0 + r0 + k - 1) * 128 + g * 8;
#pragma unroll
            for (int kt = 0; kt < 4; ++kt){
                bf16x8 z = {0,0,0,0,0,0,0,0};
                a[k][kt] = valid ? *(const bf16x8*)(ap + kt * 32) : z;
            }
        }
#pragma unroll
        for (int nt = 0; nt < 8; ++nt){
            const int col = nt * 16 + r0;
            float bv = cbias[col];
            f32x4 acc = {bv, bv, bv, bv};
#pragma unroll
            for (int k = 0; k < 3; ++k)
#pragma unroll
                for (int kt = 0; kt < 4; ++kt)
                    acc = __builtin_amdgcn_mfma_f32_16x16x32_bf16(
                            a[k][kt], *(const bf16x8*)(cWk + k * 16384 + col * 128 + kt * 32 + g * 8),
                            acc, 0, 0, 0);
#pragma unroll
            for (int q = 0; q < 4; ++q){
                int row = lr0 + g * 4 + q;
                bufA[row * 128 + (col ^ ((row & 7) << 3))] = f2b(acc[q]);
            }
        }
    }
    __syncthreads();
    // ---- ssm: bufA -> bufB ----
    {
        bf16x8 a[4];
#pragma unroll
        for (int kt = 0; kt < 4; ++kt)
            a[kt] = *(const bf16x8*)(&bufA[(lr0 + r0) * 128 + ((kt * 32 + g * 8) ^ ((r0 & 7) << 3))]);
#pragma unroll
        for (int nt = 0; nt < 8; ++nt){
            const int col = nt * 16 + r0;
            float bv = sbias[col];
            f32x4 acc = {bv, bv, bv, bv};
#pragma unroll
            for (int kt = 0; kt < 4; ++kt)
                acc = __builtin_amdgcn_mfma_f32_16x16x32_bf16(
                        a[kt], *(const bf16x8*)(sW + col * 128 + kt * 32 + g * 8), acc, 0, 0, 0);
#pragma unroll
            for (int q = 0; q < 4; ++q){
                int row = lr0 + g * 4 + q;
                bufB[row * 128 + (col ^ ((row & 7) << 3))] = f2b(acc[q]);
            }
        }
    }
    __syncthreads();
    // ---- outp + resid: bufB -> bufA ----
    {
        bf16x8 a[4];
#pragma unroll
        for (int kt = 0; kt < 4; ++kt)
            a[kt] = *(const bf16x8*)(&bufB[(lr0 + r0) * 128 + ((kt * 32 + g * 8) ^ ((r0 & 7) << 3))]);
#pragma unroll
        for (int nt = 0; nt < 8; ++nt){
            const int col = nt * 16 + r0;
            float bv = obias[col];
            f32x4 acc = {bv, bv, bv, bv};
#pragma unroll
            for (int kt = 0; kt < 4; ++kt)
                acc = __builtin_amdgcn_mfma_f32_16x16x32_bf16(
                        a[kt], *(const bf16x8*)(oW + col * 128 + kt * 32 + g * 8), acc, 0, 0, 0);
#pragma unroll
            for (int q = 0; q < 4; ++q){
                int row = lr0 + g * 4 + q;
                float v = acc[q] + xnF[(rowbase + row) * 128 + col];
                bufA[row * 128 + (col ^ ((row & 7) << 3))] = f2b(v);
            }
        }
    }
    __syncthreads();
    // ---- proj: bufA -> out (96 cols, f32) ----
    {
        bf16x8 a[4];
#pragma unroll
        for (int kt = 0; kt < 4; ++kt)
            a[kt] = *(const bf16x8*)(&bufA[(lr0 + r0) * 128 + ((kt * 32 + g * 8) ^ ((r0 & 7) << 3))]);
#pragma unroll
        for (int nt = 0; nt < 6; ++nt){
            const int col = nt * 16 + r0;
            float bv = pbias[col];
            f32x4 acc = {bv, bv, bv, bv};
#pragma unroll
            for (int kt = 0; kt < 4; ++kt)
                acc = __builtin_amdgcn_mfma_f32_16x16x32_bf16(
                        a[kt], *(const bf16x8*)(pW + col * 128 + kt * 32 + g * 8), acc, 0, 0, 0);
#pragma unroll
            for (int q = 0; q < 4; ++q)
                out[(rowbase + lr0 + g * 4 + q) * 96 + col] = acc[q];
        }
    }
}

// ---------- launch ----------
extern "C" void kernel_launch(void* const* d_in, const int* in_sizes, int n_in,
                              void* d_out, int out_size, void* d_ws, size_t ws_size,
                              hipStream_t stream)
{
    const float* x   = (const float*)d_in[0];
    const float* eW  = (const float*)d_in[1];
    const float* eb  = (const float*)d_in[2];
    const float* lng = (const float*)d_in[3];
    const float* lnb = (const float*)d_in[4];
    const float* vW  = (const float*)d_in[9];
    const float* vb  = (const float*)d_in[10];
    const float* Wx  = (const float*)d_in[11];
    const float* Wh  = (const float*)d_in[12];
    const float* lb  = (const float*)d_in[13];
    const float* cW  = (const float*)d_in[14];
    const float* cb_ = (const float*)d_in[15];
    const float* sW  = (const float*)d_in[16];
    const float* sb  = (const float*)d_in[17];
    const float* oW  = (const float*)d_in[18];
    const float* ob  = (const float*)d_in[19];
    const float* pW  = (const float*)d_in[20];
    const float* pb  = (const float*)d_in[21];

    char* ws = (char*)d_ws;
    float*    xnF = (float*)   (ws + 0);          // 5376x128 f32   (2.75 MB)
    ushort_t* xnB = (ushort_t*)(ws + 2752512);    // 5376x128 bf16  (1.38 MB)
    ushort_t* c0B = (ushort_t*)(ws + 4128768);    // ctx0 bf16      (1.38 MB)
    float*    X0F = (float*)   (ws + 5505024);    // 5376x512 f32   (11 MB)
    ushort_t* lsB = (ushort_t*)(ws + 16515072);   // lstm out bf16  (1.38 MB)
    ushort_t* wb  = (ushort_t*)(ws + 17891328);   // bf16 weights   (0.75 MB)
    ushort_t* h0g = (ushort_t*)(ws + 18874368);   // h0 all-t bf16  (11 MB)
    ushort_t* X1B = (ushort_t*)(ws + 29884416);   // X1 bf16        (44 MB)

    prep_k<<<dim3(256, 9), 256, 0, stream>>>(vW, Wx, Wh, cW, sW, oW, pW, wb);
    embed_ln_k<<<672, 128, 0, stream>>>(x, eW, eb, lng, lnb, xnF, xnB);
    // ctx0 = xn @ vW^T + vb   (attention collapses to identity on v)
    mm16_k<<<84, 256, 0, stream>>>(xnB, wb + 0,      vb, nullptr, nullptr, c0B, 128);
    // X0 = ctx0 @ Wx0^T + b0
    mm16_k<<<84, 256, 0, stream>>>(c0B, wb + 16384,  lb, nullptr, X0F,     nullptr, 512);
    // layer-0 recurrence (writes h0 for all 64 steps)
    lstm0_k<<<42, 512, 0, stream>>>(X0F, wb + 81920, h0g);
    // X1 = h0_all @ Wx1^T + b1   (43008 x 512, full-GPU GEMM)
    mm16_k<<<672, 256, 0, stream>>>(h0g, wb + 147456, lb + 512, nullptr, nullptr, X1B, 512);
    // layer-1 recurrence
    lstm1_k<<<42, 512, 0, stream>>>(X1B, wb + 212992, lsB);
    tail_k<<<84, 256, 0, stream>>>(lsB, wb + 278528, cb_, wb + 327680, sb,
                                   wb + 344064, ob, xnF, wb + 360448, pb, (float*)d_out);
}

// Round 7
// 250.222 us; speedup vs baseline: 1.2101x; 1.2101x over previous
//
#include <hip/hip_runtime.h>

typedef unsigned short ushort_t;
typedef unsigned int uint_t;

using bf16x8 = __attribute__((ext_vector_type(8))) short;
using f32x4  = __attribute__((ext_vector_type(4))) float;
using u16x4  = __attribute__((ext_vector_type(4))) unsigned short;

// ---------- helpers ----------
__device__ __forceinline__ ushort_t f2b(float f){
    union { float f; uint_t u; } v; v.f = f;
    uint_t u = v.u;
    uint_t r = (u + 0x7FFFu + ((u >> 16) & 1u)) >> 16;   // RNE
    return (ushort_t)r;
}

// ---------- weight prep: f32 -> bf16 (+ conv restride) ----------
__global__ void prep_k(const float* __restrict__ vW, const float* __restrict__ Wx,
                       const float* __restrict__ Wh, const float* __restrict__ cW,
                       const float* __restrict__ sW, const float* __restrict__ oW,
                       const float* __restrict__ pW, ushort_t* __restrict__ wb)
{
    int idx = blockIdx.x * 256 + threadIdx.x;
    switch (blockIdx.y){
    case 0: if (idx < 16384) wb[idx]          = f2b(vW[idx]);           break;
    case 1: if (idx < 65536) wb[16384  + idx] = f2b(Wx[idx]);           break; // Wx0
    case 2: if (idx < 65536) wb[81920  + idx] = f2b(Wh[idx]);           break; // Wh0
    case 3: if (idx < 65536) wb[147456 + idx] = f2b(Wx[65536 + idx]);   break; // Wx1
    case 4: if (idx < 65536) wb[212992 + idx] = f2b(Wh[65536 + idx]);   break; // Wh1
    case 5: if (idx < 49152){                                                  // conv [k][o][i]
                int k = idx >> 14; int oi = idx & 16383;
                wb[278528 + idx] = f2b(cW[oi * 3 + k]);
            } break;
    case 6: if (idx < 16384) wb[327680 + idx] = f2b(sW[idx]);           break;
    case 7: if (idx < 16384) wb[344064 + idx] = f2b(oW[idx]);           break;
    case 8: if (idx < 12288) wb[360448 + idx] = f2b(pW[idx]);           break;
    }
}

// ---------- patch embed + layernorm ----------
__global__ void embed_ln_k(const float* __restrict__ x, const float* __restrict__ eW,
                           const float* __restrict__ eb, const float* __restrict__ lng,
                           const float* __restrict__ lnb,
                           float* __restrict__ xnF, ushort_t* __restrict__ xnB)
{
    const int e  = threadIdx.x;
    const int bc = blockIdx.x;
    const int b  = bc / 21, c = bc % 21;
    const int wid = threadIdx.x >> 6;

    float w[16];
#pragma unroll
    for (int p = 0; p < 16; ++p) w[p] = eW[e * 16 + p];
    const float bias = eb[e], gam = lng[e], bet = lnb[e];

    __shared__ float patch[16];
    __shared__ float red[4];

    for (int n = 0; n < 8; ++n){
        if (e < 16) patch[e] = x[(b * 128 + n * 16 + e) * 21 + c];
        __syncthreads();
        float v = bias;
#pragma unroll
        for (int p = 0; p < 16; ++p) v += w[p] * patch[p];

        float s = v, sq = v * v;
#pragma unroll
        for (int m = 32; m >= 1; m >>= 1){
            s  += __shfl_xor(s,  m);
            sq += __shfl_xor(sq, m);
        }
        if ((threadIdx.x & 63) == 0){ red[wid] = s; red[2 + wid] = sq; }
        __syncthreads();
        float S  = red[0] + red[1];
        float SQ = red[2] + red[3];
        float mean = S * (1.f / 128.f);
        float var  = SQ * (1.f / 128.f) - mean * mean;
        float r    = rsqrtf(var + 1e-5f);
        float y    = (v - mean) * r * gam + bet;
        int row = bc * 8 + n;
        xnF[row * 128 + e] = y;
        xnB[row * 128 + e] = f2b(y);
        __syncthreads();
    }
}

// ---------- generic MFMA matmul: Y(ROWSxOUT) = A(ROWSx128) @ W(OUTx128)^T + bias ----------
__global__ void mm16_k(const ushort_t* __restrict__ A, const ushort_t* __restrict__ W,
                       const float* __restrict__ bias, const float* __restrict__ resid,
                       float* __restrict__ outF, ushort_t* __restrict__ outB, int OUT)
{
    const int lane = threadIdx.x & 63, wave = threadIdx.x >> 6;
    const int rowbase = blockIdx.x * 64 + wave * 16;
    const int r0 = lane & 15, g = lane >> 4;

    bf16x8 a[4];
    const ushort_t* ap = A + (rowbase + r0) * 128 + g * 8;
#pragma unroll
    for (int kt = 0; kt < 4; ++kt) a[kt] = *(const bf16x8*)(ap + kt * 32);

    const int ntiles = OUT >> 4;
    for (int nt = 0; nt < ntiles; ++nt){
        const int col = nt * 16 + r0;
        float bv = bias[col];
        f32x4 acc = {bv, bv, bv, bv};
        const ushort_t* wp = W + col * 128 + g * 8;
#pragma unroll
        for (int kt = 0; kt < 4; ++kt)
            acc = __builtin_amdgcn_mfma_f32_16x16x32_bf16(a[kt], *(const bf16x8*)(wp + kt * 32), acc, 0, 0, 0);
#pragma unroll
        for (int q = 0; q < 4; ++q){
            int row = rowbase + g * 4 + q;
            float val = acc[q];
            if (resid) val += resid[row * 128 + col];
            if (outF)  outF[row * OUT + col] = val;
            if (outB)  outB[row * OUT + col] = f2b(val);
        }
    }
}

// ---------- LSTM layer 0: independent 64-step recurrence ----------
// grid 42, block 512 (8 waves). 16 batch rows/block. Only Wh0 in registers (64).
__global__ __launch_bounds__(512) void lstm0_k(
    const float* __restrict__ X0, const ushort_t* __restrict__ Wh0,
    ushort_t* __restrict__ h0g)
{
    __shared__ ushort_t h0[2][2048];
    const int tid = threadIdx.x;
    const int wid = tid >> 6, lane = tid & 63;
    const int r0 = lane & 15, g = lane >> 4;
    const int sw = r0 & 7;
    const int bcb = blockIdx.x * 16;
    const float K1 = 1.44269504f, K2 = 2.88539008f;

    for (int i = tid; i < 4096; i += 512) ((ushort_t*)h0)[i] = 0;

    bf16x8 wh0[4][4];
#pragma unroll
    for (int t4 = 0; t4 < 4; ++t4){
        const int cb = t4 * 128 + wid * 16;
#pragma unroll
        for (int kt = 0; kt < 4; ++kt)
            wh0[t4][kt] = *(const bf16x8*)(Wh0 + (cb + r0) * 128 + kt * 32 + g * 8);
    }

    float c0[4] = {0,0,0,0};
    f32x4 acc[4];
#pragma unroll
    for (int t4 = 0; t4 < 4; ++t4)
#pragma unroll
        for (int q = 0; q < 4; ++q)
            acc[t4][q] = X0[(bcb + g * 4 + q) * 4096 + t4 * 128 + wid * 16 + r0];

    __syncthreads();

    for (int t = 0; t < 64; ++t){
        const int p = t & 1;
        bf16x8 a0[4];
#pragma unroll
        for (int kt = 0; kt < 4; ++kt)
            a0[kt] = *(const bf16x8*)(&h0[p][r0 * 128 + ((kt * 32 + g * 8) ^ (sw << 3))]);
#pragma unroll
        for (int kt = 0; kt < 4; ++kt)
#pragma unroll
            for (int t4 = 0; t4 < 4; ++t4)
                acc[t4] = __builtin_amdgcn_mfma_f32_16x16x32_bf16(a0[kt], wh0[t4][kt], acc[t4], 0, 0, 0);
#pragma unroll
        for (int q = 0; q < 4; ++q){
            float iv = acc[0][q], fv = acc[1][q], gv = acc[2][q], ov = acc[3][q];
            float af = 1.f + __builtin_amdgcn_exp2f(-K1 * fv);
            float ai = 1.f + __builtin_amdgcn_exp2f(-K1 * iv);
            float bg = 1.f + __builtin_amdgcn_exp2f( K2 * gv);
            float cn = c0[q] * __builtin_amdgcn_rcpf(af)
                     + (bg - 2.f) * __builtin_amdgcn_rcpf(ai * bg);
            c0[q] = cn;
            float ao = 1.f + __builtin_amdgcn_exp2f(-K1 * ov);
            float bc = 1.f + __builtin_amdgcn_exp2f( K2 * cn);
            float hv = (bc - 2.f) * __builtin_amdgcn_rcpf(ao * bc);
            int row = g * 4 + q;
            ushort_t hb = f2b(hv);
            h0[p ^ 1][row * 128 + ((wid * 16 + r0) ^ ((row & 7) << 3))] = hb;
            h0g[((bcb + row) * 64 + t) * 128 + wid * 16 + r0] = hb;
        }
        if (t < 63){
            const int tn = (t + 1) & 7;
#pragma unroll
            for (int t4 = 0; t4 < 4; ++t4)
#pragma unroll
                for (int q = 0; q < 4; ++q)
                    acc[t4][q] = X0[(bcb + g * 4 + q) * 4096 + tn * 512 + t4 * 128 + wid * 16 + r0];
        }
        __syncthreads();
    }
}

// ---------- LSTM layer 1: 64-step recurrence, X1 computed in-kernel ----------
// grid 42, block 512. Wx1 + Wh1 BOTH in registers (128). h0(t) tile (4 KB)
// staged from h0g into swizzled double-buffered LDS: one coalesced 8B global
// load per thread per step, hidden under the previous step's compute.
__global__ __launch_bounds__(512, 2) void lstm1_k(
    const ushort_t* __restrict__ h0g, const ushort_t* __restrict__ Wx1,
    const ushort_t* __restrict__ Wh1, const float* __restrict__ lb,
    ushort_t* __restrict__ outB)
{
    __shared__ ushort_t hs[2][2048];   // h0(t) staging, swizzled
    __shared__ ushort_t h1[2][2048];
    const int tid = threadIdx.x;
    const int wid = tid >> 6, lane = tid & 63;
    const int r0 = lane & 15, g = lane >> 4;
    const int sw = r0 & 7;
    const int bcb = blockIdx.x * 16;
    const float K1 = 1.44269504f, K2 = 2.88539008f;

    // staging: thread loads 8B (4 bf16) of row sr, cols sc0..sc0+3
    const int sr  = tid >> 5;           // 0..15
    const int sc0 = (tid & 31) * 4;     // 0..124
    const int sdst = sr * 128 + (((sc0 & ~7) ^ ((sr & 7) << 3)) | (sc0 & 7));
    const ushort_t* hsrc = h0g + (bcb + sr) * 8192 + sc0;   // + t*128

    for (int i = tid; i < 4096; i += 512) ((ushort_t*)h1)[i] = 0;

    bf16x8 wx1r[4][4], wh1r[4][4];
#pragma unroll
    for (int t4 = 0; t4 < 4; ++t4){
        const int cb = t4 * 128 + wid * 16;
#pragma unroll
        for (int kt = 0; kt < 4; ++kt){
            wx1r[t4][kt] = *(const bf16x8*)(Wx1 + (cb + r0) * 128 + kt * 32 + g * 8);
            wh1r[t4][kt] = *(const bf16x8*)(Wh1 + (cb + r0) * 128 + kt * 32 + g * 8);
        }
    }
    float b1v[4];
#pragma unroll
    for (int t4 = 0; t4 < 4; ++t4) b1v[t4] = lb[512 + t4 * 128 + wid * 16 + r0];

    float c1[4] = {0,0,0,0};

    // prologue: stage h0(0)
    *(u16x4*)(&hs[0][sdst]) = *(const u16x4*)(hsrc);
    __syncthreads();

    for (int t = 0; t < 64; ++t){
        const int p = t & 1;

        // issue next tile's global load early (consumed just before the barrier)
        u16x4 hnx;
        if (t < 63) hnx = *(const u16x4*)(hsrc + (t + 1) * 128);

        bf16x8 ax[4], ah[4];
#pragma unroll
        for (int kt = 0; kt < 4; ++kt){
            const int off = (kt * 32 + g * 8) ^ (sw << 3);
            ax[kt] = *(const bf16x8*)(&hs[p][r0 * 128 + off]);
            ah[kt] = *(const bf16x8*)(&h1[p][r0 * 128 + off]);
        }

        f32x4 acc[4];
#pragma unroll
        for (int t4 = 0; t4 < 4; ++t4){
            f32x4 tmp = {b1v[t4], b1v[t4], b1v[t4], b1v[t4]};
            acc[t4] = tmp;
        }
#pragma unroll
        for (int kt = 0; kt < 4; ++kt)
#pragma unroll
            for (int t4 = 0; t4 < 4; ++t4){
                acc[t4] = __builtin_amdgcn_mfma_f32_16x16x32_bf16(ax[kt], wx1r[t4][kt], acc[t4], 0, 0, 0);
                acc[t4] = __builtin_amdgcn_mfma_f32_16x16x32_bf16(ah[kt], wh1r[t4][kt], acc[t4], 0, 0, 0);
            }

#pragma unroll
        for (int q = 0; q < 4; ++q){
            float iv = acc[0][q], fv = acc[1][q], gv = acc[2][q], ov = acc[3][q];
            float af = 1.f + __builtin_amdgcn_exp2f(-K1 * fv);
            float ai = 1.f + __builtin_amdgcn_exp2f(-K1 * iv);
            float bg = 1.f + __builtin_amdgcn_exp2f( K2 * gv);
            float cn = c1[q] * __builtin_amdgcn_rcpf(af)
                     + (bg - 2.f) * __builtin_amdgcn_rcpf(ai * bg);
            c1[q] = cn;
            float ao = 1.f + __builtin_amdgcn_exp2f(-K1 * ov);
            float bc = 1.f + __builtin_amdgcn_exp2f( K2 * cn);
            float hv = (bc - 2.f) * __builtin_amdgcn_rcpf(ao * bc);
            int row = g * 4 + q;
            ushort_t hb = f2b(hv);
            h1[p ^ 1][row * 128 + ((wid * 16 + r0) ^ ((row & 7) << 3))] = hb;
            if (t >= 56)
                outB[((bcb + row) * 8 + (t & 7)) * 128 + wid * 16 + r0] = hb;
        }

        // write the prefetched h0(t+1) tile into the other stage buffer
        if (t < 63) *(u16x4*)(&hs[p ^ 1][sdst]) = hnx;
        __syncthreads();
    }
}

// ---------- fused tail: conv1d(SAME,K=3) -> ssm -> outp(+resid xn) -> proj ----------
__global__ __launch_bounds__(256) void tail_k(
    const ushort_t* __restrict__ ls, const ushort_t* __restrict__ cWk,
    const float* __restrict__ cbias, const ushort_t* __restrict__ sW,
    const float* __restrict__ sbias, const ushort_t* __restrict__ oW,
    const float* __restrict__ obias, const float* __restrict__ xnF,
    const ushort_t* __restrict__ pW, const float* __restrict__ pbias,
    float* __restrict__ out)
{
    __shared__ ushort_t bufA[8192];
    __shared__ ushort_t bufB[8192];
    const int lane = threadIdx.x & 63, wave = threadIdx.x >> 6;
    const int r0 = lane & 15, g = lane >> 4;
    const int rowbase = blockIdx.x * 64;
    const int lr0 = wave * 16;

    // ---- conv ----
    {
        const int n = r0 & 7;
        bf16x8 a[3][4];
#pragma unroll
        for (int k = 0; k < 3; ++k){
            bool valid = (n + k >= 1) && (n + k <= 8);
            const ushort_t* ap = ls + (rowbase + lr0 + r0 + k - 1) * 128 + g * 8;
#pragma unroll
            for (int kt = 0; kt < 4; ++kt){
                bf16x8 z = {0,0,0,0,0,0,0,0};
                a[k][kt] = valid ? *(const bf16x8*)(ap + kt * 32) : z;
            }
        }
#pragma unroll
        for (int nt = 0; nt < 8; ++nt){
            const int col = nt * 16 + r0;
            float bv = cbias[col];
            f32x4 acc = {bv, bv, bv, bv};
#pragma unroll
            for (int k = 0; k < 3; ++k)
#pragma unroll
                for (int kt = 0; kt < 4; ++kt)
                    acc = __builtin_amdgcn_mfma_f32_16x16x32_bf16(
                            a[k][kt], *(const bf16x8*)(cWk + k * 16384 + col * 128 + kt * 32 + g * 8),
                            acc, 0, 0, 0);
#pragma unroll
            for (int q = 0; q < 4; ++q){
                int row = lr0 + g * 4 + q;
                bufA[row * 128 + (col ^ ((row & 7) << 3))] = f2b(acc[q]);
            }
        }
    }
    __syncthreads();
    // ---- ssm: bufA -> bufB ----
    {
        bf16x8 a[4];
#pragma unroll
        for (int kt = 0; kt < 4; ++kt)
            a[kt] = *(const bf16x8*)(&bufA[(lr0 + r0) * 128 + ((kt * 32 + g * 8) ^ ((r0 & 7) << 3))]);
#pragma unroll
        for (int nt = 0; nt < 8; ++nt){
            const int col = nt * 16 + r0;
            float bv = sbias[col];
            f32x4 acc = {bv, bv, bv, bv};
#pragma unroll
            for (int kt = 0; kt < 4; ++kt)
                acc = __builtin_amdgcn_mfma_f32_16x16x32_bf16(
                        a[kt], *(const bf16x8*)(sW + col * 128 + kt * 32 + g * 8), acc, 0, 0, 0);
#pragma unroll
            for (int q = 0; q < 4; ++q){
                int row = lr0 + g * 4 + q;
                bufB[row * 128 + (col ^ ((row & 7) << 3))] = f2b(acc[q]);
            }
        }
    }
    __syncthreads();
    // ---- outp + resid: bufB -> bufA ----
    {
        bf16x8 a[4];
#pragma unroll
        for (int kt = 0; kt < 4; ++kt)
            a[kt] = *(const bf16x8*)(&bufB[(lr0 + r0) * 128 + ((kt * 32 + g * 8) ^ ((r0 & 7) << 3))]);
#pragma unroll
        for (int nt = 0; nt < 8; ++nt){
            const int col = nt * 16 + r0;
            float bv = obias[col];
            f32x4 acc = {bv, bv, bv, bv};
#pragma unroll
            for (int kt = 0; kt < 4; ++kt)
                acc = __builtin_amdgcn_mfma_f32_16x16x32_bf16(
                        a[kt], *(const bf16x8*)(oW + col * 128 + kt * 32 + g * 8), acc, 0, 0, 0);
#pragma unroll
            for (int q = 0; q < 4; ++q){
                int row = lr0 + g * 4 + q;
                float v = acc[q] + xnF[(rowbase + row) * 128 + col];
                bufA[row * 128 + (col ^ ((row & 7) << 3))] = f2b(v);
            }
        }
    }
    __syncthreads();
    // ---- proj: bufA -> out (96 cols, f32) ----
    {
        bf16x8 a[4];
#pragma unroll
        for (int kt = 0; kt < 4; ++kt)
            a[kt] = *(const bf16x8*)(&bufA[(lr0 + r0) * 128 + ((kt * 32 + g * 8) ^ ((r0 & 7) << 3))]);
#pragma unroll
        for (int nt = 0; nt < 6; ++nt){
            const int col = nt * 16 + r0;
            float bv = pbias[col];
            f32x4 acc = {bv, bv, bv, bv};
#pragma unroll
            for (int kt = 0; kt < 4; ++kt)
                acc = __builtin_amdgcn_mfma_f32_16x16x32_bf16(
                        a[kt], *(const bf16x8*)(pW + col * 128 + kt * 32 + g * 8), acc, 0, 0, 0);
#pragma unroll
            for (int q = 0; q < 4; ++q)
                out[(rowbase + lr0 + g * 4 + q) * 96 + col] = acc[q];
        }
    }
}

// ---------- launch ----------
extern "C" void kernel_launch(void* const* d_in, const int* in_sizes, int n_in,
                              void* d_out, int out_size, void* d_ws, size_t ws_size,
                              hipStream_t stream)
{
    const float* x   = (const float*)d_in[0];
    const float* eW  = (const float*)d_in[1];
    const float* eb  = (const float*)d_in[2];
    const float* lng = (const float*)d_in[3];
    const float* lnb = (const float*)d_in[4];
    const float* vW  = (const float*)d_in[9];
    const float* vb  = (const float*)d_in[10];
    const float* Wx  = (const float*)d_in[11];
    const float* Wh  = (const float*)d_in[12];
    const float* lb  = (const float*)d_in[13];
    const float* cW  = (const float*)d_in[14];
    const float* cb_ = (const float*)d_in[15];
    const float* sW  = (const float*)d_in[16];
    const float* sb  = (const float*)d_in[17];
    const float* oW  = (const float*)d_in[18];
    const float* ob  = (const float*)d_in[19];
    const float* pW  = (const float*)d_in[20];
    const float* pb  = (const float*)d_in[21];

    char* ws = (char*)d_ws;
    float*    xnF = (float*)   (ws + 0);          // 5376x128 f32   (2.75 MB)
    ushort_t* xnB = (ushort_t*)(ws + 2752512);    // 5376x128 bf16  (1.38 MB)
    ushort_t* c0B = (ushort_t*)(ws + 4128768);    // ctx0 bf16      (1.38 MB)
    float*    X0F = (float*)   (ws + 5505024);    // 5376x512 f32   (11 MB)
    ushort_t* lsB = (ushort_t*)(ws + 16515072);   // lstm out bf16  (1.38 MB)
    ushort_t* wb  = (ushort_t*)(ws + 17891328);   // bf16 weights   (0.75 MB)
    ushort_t* h0g = (ushort_t*)(ws + 18874368);   // h0 all-t bf16  (11 MB)

    prep_k<<<dim3(256, 9), 256, 0, stream>>>(vW, Wx, Wh, cW, sW, oW, pW, wb);
    embed_ln_k<<<672, 128, 0, stream>>>(x, eW, eb, lng, lnb, xnF, xnB);
    // ctx0 = xn @ vW^T + vb   (attention collapses to identity on v)
    mm16_k<<<84, 256, 0, stream>>>(xnB, wb + 0,      vb, nullptr, nullptr, c0B, 128);
    // X0 = ctx0 @ Wx0^T + b0
    mm16_k<<<84, 256, 0, stream>>>(c0B, wb + 16384,  lb, nullptr, X0F,     nullptr, 512);
    // layer-0 recurrence (writes h0 for all 64 steps)
    lstm0_k<<<42, 512, 0, stream>>>(X0F, wb + 81920, h0g);
    // layer-1 recurrence (computes Wx1@h0 in-kernel, Wx1+Wh1 in registers)
    lstm1_k<<<42, 512, 0, stream>>>(h0g, wb + 147456, wb + 212992, lb, lsB);
    tail_k<<<84, 256, 0, stream>>>(lsB, wb + 278528, cb_, wb + 327680, sb,
                                   wb + 344064, ob, xnF, wb + 360448, pb, (float*)d_out);
}

// Round 8
// 229.893 us; speedup vs baseline: 1.3171x; 1.0884x over previous
//
#include <hip/hip_runtime.h>

typedef unsigned short ushort_t;
typedef unsigned int uint_t;

using bf16x8 = __attribute__((ext_vector_type(8))) short;
using f32x4  = __attribute__((ext_vector_type(4))) float;

// ---------- helpers ----------
__device__ __forceinline__ ushort_t f2b(float f){
    union { float f; uint_t u; } v; v.f = f;
    uint_t u = v.u;
    uint_t r = (u + 0x7FFFu + ((u >> 16) & 1u)) >> 16;   // RNE
    return (ushort_t)r;
}

// ---------- weight prep: f32 -> bf16 (+ conv restride) ----------
__global__ void prep_k(const float* __restrict__ vW, const float* __restrict__ Wx,
                       const float* __restrict__ Wh, const float* __restrict__ cW,
                       const float* __restrict__ sW, const float* __restrict__ oW,
                       const float* __restrict__ pW, ushort_t* __restrict__ wb)
{
    int idx = blockIdx.x * 256 + threadIdx.x;
    switch (blockIdx.y){
    case 0: if (idx < 16384) wb[idx]          = f2b(vW[idx]);           break;
    case 1: if (idx < 65536) wb[16384  + idx] = f2b(Wx[idx]);           break; // Wx0
    case 2: if (idx < 65536) wb[81920  + idx] = f2b(Wh[idx]);           break; // Wh0
    case 3: if (idx < 65536) wb[147456 + idx] = f2b(Wx[65536 + idx]);   break; // Wx1
    case 4: if (idx < 65536) wb[212992 + idx] = f2b(Wh[65536 + idx]);   break; // Wh1
    case 5: if (idx < 49152){                                                  // conv [k][o][i]
                int k = idx >> 14; int oi = idx & 16383;
                wb[278528 + idx] = f2b(cW[oi * 3 + k]);
            } break;
    case 6: if (idx < 16384) wb[327680 + idx] = f2b(sW[idx]);           break;
    case 7: if (idx < 16384) wb[344064 + idx] = f2b(oW[idx]);           break;
    case 8: if (idx < 12288) wb[360448 + idx] = f2b(pW[idx]);           break;
    }
}

// ---------- fused head: embed + layernorm -> c0 = xn@vW^T+vb -> X0 = c0@Wx0^T+b0 ----------
// grid 336, block 64 (ONE wave, 16 rows, zero barriers). xn & c0 live only in LDS.
__global__ __launch_bounds__(64) void head_k(
    const float* __restrict__ x, const float* __restrict__ eW,
    const float* __restrict__ eb, const float* __restrict__ lng,
    const float* __restrict__ lnb, const ushort_t* __restrict__ vWb,
    const float* __restrict__ vb, const ushort_t* __restrict__ wx0b,
    const float* __restrict__ lb, float* __restrict__ xnF, float* __restrict__ X0F)
{
    __shared__ ushort_t xnL[2048];   // 16x128 bf16, swizzled
    __shared__ ushort_t c0L[2048];

    const int lane = threadIdx.x;
    const int rowbase = blockIdx.x * 16;
    const int e0 = lane, e1 = lane + 64;

    float w0[16], w1[16];
#pragma unroll
    for (int p = 0; p < 16; ++p){ w0[p] = eW[e0 * 16 + p]; w1[p] = eW[e1 * 16 + p]; }
    const float bi0 = eb[e0], bi1 = eb[e1];
    const float ga0 = lng[e0], ga1 = lng[e1];
    const float be0 = lnb[e0], be1 = lnb[e1];

    for (int i = 0; i < 16; ++i){
        const int row = rowbase + i;
        const int bc = row >> 3, n = row & 7;
        const int b = bc / 21, c = bc % 21;
        const float* xp = x + (b * 128 + n * 16) * 21 + c;
        float v0 = bi0, v1 = bi1;
#pragma unroll
        for (int p = 0; p < 16; ++p){
            float pv = xp[p * 21];
            v0 += w0[p] * pv; v1 += w1[p] * pv;
        }
        float s = v0 + v1, sq = v0 * v0 + v1 * v1;
#pragma unroll
        for (int m = 32; m >= 1; m >>= 1){
            s  += __shfl_xor(s,  m);
            sq += __shfl_xor(sq, m);
        }
        float mean = s * (1.f / 128.f);
        float var  = sq * (1.f / 128.f) - mean * mean;
        float r    = rsqrtf(var + 1e-5f);
        float y0 = (v0 - mean) * r * ga0 + be0;
        float y1 = (v1 - mean) * r * ga1 + be1;
        xnF[row * 128 + e0] = y0;
        xnF[row * 128 + e1] = y1;
        const int sz = (i & 7) << 3;
        xnL[i * 128 + (e0 ^ sz)] = f2b(y0);
        xnL[i * 128 + (e1 ^ sz)] = f2b(y1);
    }

    const int r0 = lane & 15, g = lane >> 4, sw = r0 & 7;
    // c0 = xn @ vW^T + vb  -> c0L
    {
        bf16x8 a[4];
#pragma unroll
        for (int kt = 0; kt < 4; ++kt)
            a[kt] = *(const bf16x8*)(&xnL[r0 * 128 + ((kt * 32 + g * 8) ^ (sw << 3))]);
#pragma unroll
        for (int nt = 0; nt < 8; ++nt){
            const int col = nt * 16 + r0;
            float bv = vb[col];
            f32x4 acc = {bv, bv, bv, bv};
#pragma unroll
            for (int kt = 0; kt < 4; ++kt)
                acc = __builtin_amdgcn_mfma_f32_16x16x32_bf16(
                        a[kt], *(const bf16x8*)(vWb + col * 128 + kt * 32 + g * 8), acc, 0, 0, 0);
#pragma unroll
            for (int q = 0; q < 4; ++q){
                int rr = g * 4 + q;
                c0L[rr * 128 + (col ^ ((rr & 7) << 3))] = f2b(acc[q]);
            }
        }
    }
    // X0 = c0 @ Wx0^T + b0  -> X0F (f32, [row5376][512])
    {
        bf16x8 a[4];
#pragma unroll
        for (int kt = 0; kt < 4; ++kt)
            a[kt] = *(const bf16x8*)(&c0L[r0 * 128 + ((kt * 32 + g * 8) ^ (sw << 3))]);
        for (int nt = 0; nt < 32; ++nt){
            const int col = nt * 16 + r0;
            float bv = lb[col];
            f32x4 acc = {bv, bv, bv, bv};
#pragma unroll
            for (int kt = 0; kt < 4; ++kt)
                acc = __builtin_amdgcn_mfma_f32_16x16x32_bf16(
                        a[kt], *(const bf16x8*)(wx0b + col * 128 + kt * 32 + g * 8), acc, 0, 0, 0);
#pragma unroll
            for (int q = 0; q < 4; ++q)
                X0F[(rowbase + g * 4 + q) * 512 + col] = acc[q];
        }
    }
}

// ---------- LSTM layer 0: independent 64-step recurrence ----------
// grid 42, block 512 (8 waves). 16 batch rows/block. Only Wh0 in registers.
// h0g written per block-step contiguous: [blk][t][row 16][col 128] bf16.
__global__ __launch_bounds__(512) void lstm0_k(
    const float* __restrict__ X0, const ushort_t* __restrict__ Wh0,
    ushort_t* __restrict__ h0g)
{
    __shared__ ushort_t h0[2][2048];
    const int tid = threadIdx.x;
    const int wid = tid >> 6, lane = tid & 63;
    const int r0 = lane & 15, g = lane >> 4;
    const int sw = r0 & 7;
    const int bcb = blockIdx.x * 16;
    const float K1 = 1.44269504f, K2 = 2.88539008f;

    for (int i = tid; i < 4096; i += 512) ((ushort_t*)h0)[i] = 0;

    bf16x8 wh0[4][4];
#pragma unroll
    for (int t4 = 0; t4 < 4; ++t4){
        const int cb = t4 * 128 + wid * 16;
#pragma unroll
        for (int kt = 0; kt < 4; ++kt)
            wh0[t4][kt] = *(const bf16x8*)(Wh0 + (cb + r0) * 128 + kt * 32 + g * 8);
    }

    float c0[4] = {0,0,0,0};
    f32x4 acc[4];
#pragma unroll
    for (int t4 = 0; t4 < 4; ++t4)
#pragma unroll
        for (int q = 0; q < 4; ++q)
            acc[t4][q] = X0[(bcb + g * 4 + q) * 4096 + t4 * 128 + wid * 16 + r0];

    ushort_t* h0gb = h0g + blockIdx.x * 131072;   // 64 t x 2048

    __syncthreads();

    for (int t = 0; t < 64; ++t){
        const int p = t & 1;
        bf16x8 a0[4];
#pragma unroll
        for (int kt = 0; kt < 4; ++kt)
            a0[kt] = *(const bf16x8*)(&h0[p][r0 * 128 + ((kt * 32 + g * 8) ^ (sw << 3))]);
#pragma unroll
        for (int kt = 0; kt < 4; ++kt)
#pragma unroll
            for (int t4 = 0; t4 < 4; ++t4)
                acc[t4] = __builtin_amdgcn_mfma_f32_16x16x32_bf16(a0[kt], wh0[t4][kt], acc[t4], 0, 0, 0);
#pragma unroll
        for (int q = 0; q < 4; ++q){
            float iv = acc[0][q], fv = acc[1][q], gv = acc[2][q], ov = acc[3][q];
            float af = 1.f + __builtin_amdgcn_exp2f(-K1 * fv);
            float ai = 1.f + __builtin_amdgcn_exp2f(-K1 * iv);
            float bg = 1.f + __builtin_amdgcn_exp2f( K2 * gv);
            float cn = c0[q] * __builtin_amdgcn_rcpf(af)
                     + (bg - 2.f) * __builtin_amdgcn_rcpf(ai * bg);
            c0[q] = cn;
            float ao = 1.f + __builtin_amdgcn_exp2f(-K1 * ov);
            float bc = 1.f + __builtin_amdgcn_exp2f( K2 * cn);
            float hv = (bc - 2.f) * __builtin_amdgcn_rcpf(ao * bc);
            int row = g * 4 + q;
            ushort_t hb = f2b(hv);
            h0[p ^ 1][row * 128 + ((wid * 16 + r0) ^ ((row & 7) << 3))] = hb;
            h0gb[t * 2048 + row * 128 + wid * 16 + r0] = hb;
        }
        if (t < 63){
            const int tn = (t + 1) & 7;
#pragma unroll
            for (int t4 = 0; t4 < 4; ++t4)
#pragma unroll
                for (int q = 0; q < 4; ++q)
                    acc[t4][q] = X0[(bcb + g * 4 + q) * 4096 + tn * 512 + t4 * 128 + wid * 16 + r0];
        }
        __syncthreads();
    }
}

// ---------- LSTM layer 1: 64-step recurrence; A-operand of Wx1 read straight
// from h0g into registers (prefetched one step ahead); Wx1+Wh1 register/AGPR-resident.
__global__ __launch_bounds__(512, 2) void lstm1_k(
    const ushort_t* __restrict__ h0g, const ushort_t* __restrict__ Wx1,
    const ushort_t* __restrict__ Wh1, const float* __restrict__ lb,
    ushort_t* __restrict__ outB)
{
    __shared__ ushort_t h1[2][2048];
    const int tid = threadIdx.x;
    const int wid = tid >> 6, lane = tid & 63;
    const int r0 = lane & 15, g = lane >> 4;
    const int sw = r0 & 7;
    const int bcb = blockIdx.x * 16;
    const float K1 = 1.44269504f, K2 = 2.88539008f;

    for (int i = tid; i < 4096; i += 512) ((ushort_t*)h1)[i] = 0;

    bf16x8 wx1r[4][4], wh1r[4][4];
#pragma unroll
    for (int t4 = 0; t4 < 4; ++t4){
        const int cb = t4 * 128 + wid * 16;
#pragma unroll
        for (int kt = 0; kt < 4; ++kt){
            wx1r[t4][kt] = *(const bf16x8*)(Wx1 + (cb + r0) * 128 + kt * 32 + g * 8);
            wh1r[t4][kt] = *(const bf16x8*)(Wh1 + (cb + r0) * 128 + kt * 32 + g * 8);
        }
    }
    float b1v[4];
#pragma unroll
    for (int t4 = 0; t4 < 4; ++t4) b1v[t4] = lb[512 + t4 * 128 + wid * 16 + r0];

    float c1[4] = {0,0,0,0};

    // per-lane A-fragment base inside this block's h0g slice
    const ushort_t* axb = h0g + blockIdx.x * 131072 + r0 * 128 + g * 8;

    bf16x8 axc[4];
#pragma unroll
    for (int kt = 0; kt < 4; ++kt) axc[kt] = *(const bf16x8*)(axb + kt * 32);   // t=0

    __syncthreads();

    for (int t = 0; t < 64; ++t){
        const int p = t & 1;

        // prefetch h0(t+1) fragments (global, no sync needed — producer kernel done)
        bf16x8 axn[4];
        if (t < 63){
#pragma unroll
            for (int kt = 0; kt < 4; ++kt)
                axn[kt] = *(const bf16x8*)(axb + (t + 1) * 2048 + kt * 32);
        }

        bf16x8 ah[4];
#pragma unroll
        for (int kt = 0; kt < 4; ++kt)
            ah[kt] = *(const bf16x8*)(&h1[p][r0 * 128 + ((kt * 32 + g * 8) ^ (sw << 3))]);

        f32x4 acc[4];
#pragma unroll
        for (int t4 = 0; t4 < 4; ++t4){
            f32x4 tmp = {b1v[t4], b1v[t4], b1v[t4], b1v[t4]};
            acc[t4] = tmp;
        }
#pragma unroll
        for (int kt = 0; kt < 4; ++kt)
#pragma unroll
            for (int t4 = 0; t4 < 4; ++t4){
                acc[t4] = __builtin_amdgcn_mfma_f32_16x16x32_bf16(axc[kt], wx1r[t4][kt], acc[t4], 0, 0, 0);
                acc[t4] = __builtin_amdgcn_mfma_f32_16x16x32_bf16(ah[kt],  wh1r[t4][kt], acc[t4], 0, 0, 0);
            }

#pragma unroll
        for (int q = 0; q < 4; ++q){
            float iv = acc[0][q], fv = acc[1][q], gv = acc[2][q], ov = acc[3][q];
            float af = 1.f + __builtin_amdgcn_exp2f(-K1 * fv);
            float ai = 1.f + __builtin_amdgcn_exp2f(-K1 * iv);
            float bg = 1.f + __builtin_amdgcn_exp2f( K2 * gv);
            float cn = c1[q] * __builtin_amdgcn_rcpf(af)
                     + (bg - 2.f) * __builtin_amdgcn_rcpf(ai * bg);
            c1[q] = cn;
            float ao = 1.f + __builtin_amdgcn_exp2f(-K1 * ov);
            float bc = 1.f + __builtin_amdgcn_exp2f( K2 * cn);
            float hv = (bc - 2.f) * __builtin_amdgcn_rcpf(ao * bc);
            int row = g * 4 + q;
            ushort_t hb = f2b(hv);
            h1[p ^ 1][row * 128 + ((wid * 16 + r0) ^ ((row & 7) << 3))] = hb;
            if (t >= 56)
                outB[((bcb + row) * 8 + (t & 7)) * 128 + wid * 16 + r0] = hb;
        }

        if (t < 63){
#pragma unroll
            for (int kt = 0; kt < 4; ++kt) axc[kt] = axn[kt];
        }
        __syncthreads();
    }
}

// ---------- fused tail: conv1d(SAME,K=3) -> ssm -> outp(+resid xn) -> proj ----------
__global__ __launch_bounds__(256) void tail_k(
    const ushort_t* __restrict__ ls, const ushort_t* __restrict__ cWk,
    const float* __restrict__ cbias, const ushort_t* __restrict__ sW,
    const float* __restrict__ sbias, const ushort_t* __restrict__ oW,
    const float* __restrict__ obias, const float* __restrict__ xnF,
    const ushort_t* __restrict__ pW, const float* __restrict__ pbias,
    float* __restrict__ out)
{
    __shared__ ushort_t bufA[8192];
    __shared__ ushort_t bufB[8192];
    const int lane = threadIdx.x & 63, wave = threadIdx.x >> 6;
    const int r0 = lane & 15, g = lane >> 4;
    const int rowbase = blockIdx.x * 64;
    const int lr0 = wave * 16;

    // ---- conv ----
    {
        const int n = r0 & 7;
        bf16x8 a[3][4];
#pragma unroll
        for (int k = 0; k < 3; ++k){
            bool valid = (n + k >= 1) && (n + k <= 8);
            const ushort_t* ap = ls + (rowbase + lr0 + r0 + k - 1) * 128 + g * 8;
#pragma unroll
            for (int kt = 0; kt < 4; ++kt){
                bf16x8 z = {0,0,0,0,0,0,0,0};
                a[k][kt] = valid ? *(const bf16x8*)(ap + kt * 32) : z;
            }
        }
#pragma unroll
        for (int nt = 0; nt < 8; ++nt){
            const int col = nt * 16 + r0;
            float bv = cbias[col];
            f32x4 acc = {bv, bv, bv, bv};
#pragma unroll
            for (int k = 0; k < 3; ++k)
#pragma unroll
                for (int kt = 0; kt < 4; ++kt)
                    acc = __builtin_amdgcn_mfma_f32_16x16x32_bf16(
                            a[k][kt], *(const bf16x8*)(cWk + k * 16384 + col * 128 + kt * 32 + g * 8),
                            acc, 0, 0, 0);
#pragma unroll
            for (int q = 0; q < 4; ++q){
                int row = lr0 + g * 4 + q;
                bufA[row * 128 + (col ^ ((row & 7) << 3))] = f2b(acc[q]);
            }
        }
    }
    __syncthreads();
    // ---- ssm: bufA -> bufB ----
    {
        bf16x8 a[4];
#pragma unroll
        for (int kt = 0; kt < 4; ++kt)
            a[kt] = *(const bf16x8*)(&bufA[(lr0 + r0) * 128 + ((kt * 32 + g * 8) ^ ((r0 & 7) << 3))]);
#pragma unroll
        for (int nt = 0; nt < 8; ++nt){
            const int col = nt * 16 + r0;
            float bv = sbias[col];
            f32x4 acc = {bv, bv, bv, bv};
#pragma unroll
            for (int kt = 0; kt < 4; ++kt)
                acc = __builtin_amdgcn_mfma_f32_16x16x32_bf16(
                        a[kt], *(const bf16x8*)(sW + col * 128 + kt * 32 + g * 8), acc, 0, 0, 0);
#pragma unroll
            for (int q = 0; q < 4; ++q){
                int row = lr0 + g * 4 + q;
                bufB[row * 128 + (col ^ ((row & 7) << 3))] = f2b(acc[q]);
            }
        }
    }
    __syncthreads();
    // ---- outp + resid: bufB -> bufA ----
    {
        bf16x8 a[4];
#pragma unroll
        for (int kt = 0; kt < 4; ++kt)
            a[kt] = *(const bf16x8*)(&bufB[(lr0 + r0) * 128 + ((kt * 32 + g * 8) ^ ((r0 & 7) << 3))]);
#pragma unroll
        for (int nt = 0; nt < 8; ++nt){
            const int col = nt * 16 + r0;
            float bv = obias[col];
            f32x4 acc = {bv, bv, bv, bv};
#pragma unroll
            for (int kt = 0; kt < 4; ++kt)
                acc = __builtin_amdgcn_mfma_f32_16x16x32_bf16(
                        a[kt], *(const bf16x8*)(oW + col * 128 + kt * 32 + g * 8), acc, 0, 0, 0);
#pragma unroll
            for (int q = 0; q < 4; ++q){
                int row = lr0 + g * 4 + q;
                float v = acc[q] + xnF[(rowbase + row) * 128 + col];
                bufA[row * 128 + (col ^ ((row & 7) << 3))] = f2b(v);
            }
        }
    }
    __syncthreads();
    // ---- proj: bufA -> out (96 cols, f32) ----
    {
        bf16x8 a[4];
#pragma unroll
        for (int kt = 0; kt < 4; ++kt)
            a[kt] = *(const bf16x8*)(&bufA[(lr0 + r0) * 128 + ((kt * 32 + g * 8) ^ ((r0 & 7) << 3))]);
#pragma unroll
        for (int nt = 0; nt < 6; ++nt){
            const int col = nt * 16 + r0;
            float bv = pbias[col];
            f32x4 acc = {bv, bv, bv, bv};
#pragma unroll
            for (int kt = 0; kt < 4; ++kt)
                acc = __builtin_amdgcn_mfma_f32_16x16x32_bf16(
                        a[kt], *(const bf16x8*)(pW + col * 128 + kt * 32 + g * 8), acc, 0, 0, 0);
#pragma unroll
            for (int q = 0; q < 4; ++q)
                out[(rowbase + lr0 + g * 4 + q) * 96 + col] = acc[q];
        }
    }
}

// ---------- launch ----------
extern "C" void kernel_launch(void* const* d_in, const int* in_sizes, int n_in,
                              void* d_out, int out_size, void* d_ws, size_t ws_size,
                              hipStream_t stream)
{
    const float* x   = (const float*)d_in[0];
    const float* eW  = (const float*)d_in[1];
    const float* eb  = (const float*)d_in[2];
    const float* lng = (const float*)d_in[3];
    const float* lnb = (const float*)d_in[4];
    const float* vW  = (const float*)d_in[9];
    const float* vb  = (const float*)d_in[10];
    const float* Wx  = (const float*)d_in[11];
    const float* Wh  = (const float*)d_in[12];
    const float* lb  = (const float*)d_in[13];
    const float* cW  = (const float*)d_in[14];
    const float* cb_ = (const float*)d_in[15];
    const float* sW  = (const float*)d_in[16];
    const float* sb  = (const float*)d_in[17];
    const float* oW  = (const float*)d_in[18];
    const float* ob  = (const float*)d_in[19];
    const float* pW  = (const float*)d_in[20];
    const float* pb  = (const float*)d_in[21];

    char* ws = (char*)d_ws;
    float*    xnF = (float*)   (ws + 0);          // 5376x128 f32   (2.75 MB)
    float*    X0F = (float*)   (ws + 5505024);    // 5376x512 f32   (11 MB)
    ushort_t* lsB = (ushort_t*)(ws + 16515072);   // lstm out bf16  (1.38 MB)
    ushort_t* wb  = (ushort_t*)(ws + 17891328);   // bf16 weights   (0.75 MB)
    ushort_t* h0g = (ushort_t*)(ws + 18874368);   // h0 [blk][t][16][128] bf16 (11 MB)

    prep_k<<<dim3(256, 9), 256, 0, stream>>>(vW, Wx, Wh, cW, sW, oW, pW, wb);
    // fused embed+LN -> c0 -> X0 (single-wave blocks, no barriers)
    head_k<<<336, 64, 0, stream>>>(x, eW, eb, lng, lnb, wb + 0, vb, wb + 16384, lb,
                                   xnF, X0F);
    // layer-0 recurrence (h0g per-block step-contiguous for lstm1 frag reads)
    lstm0_k<<<42, 512, 0, stream>>>(X0F, wb + 81920, h0g);
    // layer-1 recurrence (ax from h0g global, register-prefetched)
    lstm1_k<<<42, 512, 0, stream>>>(h0g, wb + 147456, wb + 212992, lb, lsB);
    tail_k<<<84, 256, 0, stream>>>(lsB, wb + 278528, cb_, wb + 327680, sb,
                                   wb + 344064, ob, xnF, wb + 360448, pb, (float*)d_out);
}

// Round 9
// 208.379 us; speedup vs baseline: 1.4530x; 1.1032x over previous
//
#include <hip/hip_runtime.h>

typedef unsigned short ushort_t;
typedef unsigned int uint_t;

using bf16x8 = __attribute__((ext_vector_type(8))) short;
using f32x4  = __attribute__((ext_vector_type(4))) float;

// ---------- helpers ----------
__device__ __forceinline__ ushort_t f2b(float f){
    union { float f; uint_t u; } v; v.f = f;
    uint_t u = v.u;
    uint_t r = (u + 0x7FFFu + ((u >> 16) & 1u)) >> 16;   // RNE
    return (ushort_t)r;
}

// ---------- weight prep: f32 -> bf16 (+ conv restride) ----------
__global__ void prep_k(const float* __restrict__ vW, const float* __restrict__ Wx,
                       const float* __restrict__ Wh, const float* __restrict__ cW,
                       const float* __restrict__ sW, const float* __restrict__ oW,
                       const float* __restrict__ pW, ushort_t* __restrict__ wb)
{
    int idx = blockIdx.x * 256 + threadIdx.x;
    switch (blockIdx.y){
    case 0: if (idx < 16384) wb[idx]          = f2b(vW[idx]);           break;
    case 1: if (idx < 65536) wb[16384  + idx] = f2b(Wx[idx]);           break; // Wx0
    case 2: if (idx < 65536) wb[81920  + idx] = f2b(Wh[idx]);           break; // Wh0
    case 3: if (idx < 65536) wb[147456 + idx] = f2b(Wx[65536 + idx]);   break; // Wx1
    case 4: if (idx < 65536) wb[212992 + idx] = f2b(Wh[65536 + idx]);   break; // Wh1
    case 5: if (idx < 49152){                                                  // conv [k][o][i]
                int k = idx >> 14; int oi = idx & 16383;
                wb[278528 + idx] = f2b(cW[oi * 3 + k]);
            } break;
    case 6: if (idx < 16384) wb[327680 + idx] = f2b(sW[idx]);           break;
    case 7: if (idx < 16384) wb[344064 + idx] = f2b(oW[idx]);           break;
    case 8: if (idx < 12288) wb[360448 + idx] = f2b(pW[idx]);           break;
    }
}

// ---------- fused head: embed + layernorm -> c0 = xn@vW^T+vb -> X0 = c0@Wx0^T+b0 ----------
// grid 336, block 64 (ONE wave, 16 rows, zero barriers). xn & c0 live only in LDS.
__global__ __launch_bounds__(64) void head_k(
    const float* __restrict__ x, const float* __restrict__ eW,
    const float* __restrict__ eb, const float* __restrict__ lng,
    const float* __restrict__ lnb, const ushort_t* __restrict__ vWb,
    const float* __restrict__ vb, const ushort_t* __restrict__ wx0b,
    const float* __restrict__ lb, float* __restrict__ xnF, float* __restrict__ X0F)
{
    __shared__ ushort_t xnL[2048];   // 16x128 bf16, swizzled
    __shared__ ushort_t c0L[2048];

    const int lane = threadIdx.x;
    const int rowbase = blockIdx.x * 16;
    const int e0 = lane, e1 = lane + 64;

    float w0[16], w1[16];
#pragma unroll
    for (int p = 0; p < 16; ++p){ w0[p] = eW[e0 * 16 + p]; w1[p] = eW[e1 * 16 + p]; }
    const float bi0 = eb[e0], bi1 = eb[e1];
    const float ga0 = lng[e0], ga1 = lng[e1];
    const float be0 = lnb[e0], be1 = lnb[e1];

    for (int i = 0; i < 16; ++i){
        const int row = rowbase + i;
        const int bc = row >> 3, n = row & 7;
        const int b = bc / 21, c = bc % 21;
        const float* xp = x + (b * 128 + n * 16) * 21 + c;
        float v0 = bi0, v1 = bi1;
#pragma unroll
        for (int p = 0; p < 16; ++p){
            float pv = xp[p * 21];
            v0 += w0[p] * pv; v1 += w1[p] * pv;
        }
        float s = v0 + v1, sq = v0 * v0 + v1 * v1;
#pragma unroll
        for (int m = 32; m >= 1; m >>= 1){
            s  += __shfl_xor(s,  m);
            sq += __shfl_xor(sq, m);
        }
        float mean = s * (1.f / 128.f);
        float var  = sq * (1.f / 128.f) - mean * mean;
        float r    = rsqrtf(var + 1e-5f);
        float y0 = (v0 - mean) * r * ga0 + be0;
        float y1 = (v1 - mean) * r * ga1 + be1;
        xnF[row * 128 + e0] = y0;
        xnF[row * 128 + e1] = y1;
        const int sz = (i & 7) << 3;
        xnL[i * 128 + (e0 ^ sz)] = f2b(y0);
        xnL[i * 128 + (e1 ^ sz)] = f2b(y1);
    }

    const int r0 = lane & 15, g = lane >> 4, sw = r0 & 7;
    // c0 = xn @ vW^T + vb  -> c0L
    {
        bf16x8 a[4];
#pragma unroll
        for (int kt = 0; kt < 4; ++kt)
            a[kt] = *(const bf16x8*)(&xnL[r0 * 128 + ((kt * 32 + g * 8) ^ (sw << 3))]);
#pragma unroll
        for (int nt = 0; nt < 8; ++nt){
            const int col = nt * 16 + r0;
            float bv = vb[col];
            f32x4 acc = {bv, bv, bv, bv};
#pragma unroll
            for (int kt = 0; kt < 4; ++kt)
                acc = __builtin_amdgcn_mfma_f32_16x16x32_bf16(
                        a[kt], *(const bf16x8*)(vWb + col * 128 + kt * 32 + g * 8), acc, 0, 0, 0);
#pragma unroll
            for (int q = 0; q < 4; ++q){
                int rr = g * 4 + q;
                c0L[rr * 128 + (col ^ ((rr & 7) << 3))] = f2b(acc[q]);
            }
        }
    }
    // X0 = c0 @ Wx0^T + b0  -> X0F (f32, [row5376][512])
    {
        bf16x8 a[4];
#pragma unroll
        for (int kt = 0; kt < 4; ++kt)
            a[kt] = *(const bf16x8*)(&c0L[r0 * 128 + ((kt * 32 + g * 8) ^ (sw << 3))]);
        for (int nt = 0; nt < 32; ++nt){
            const int col = nt * 16 + r0;
            float bv = lb[col];
            f32x4 acc = {bv, bv, bv, bv};
#pragma unroll
            for (int kt = 0; kt < 4; ++kt)
                acc = __builtin_amdgcn_mfma_f32_16x16x32_bf16(
                        a[kt], *(const bf16x8*)(wx0b + col * 128 + kt * 32 + g * 8), acc, 0, 0, 0);
#pragma unroll
            for (int q = 0; q < 4; ++q)
                X0F[(rowbase + g * 4 + q) * 512 + col] = acc[q];
        }
    }
}

// ---------- fused 2-layer LSTM, layer-pipelined (65 phases) ----------
// grid 42, block 512 (8 waves, 2/SIMD). 16 batch rows/block.
// Phase ph: L0(t=ph) [ph<64] CONCURRENT WITH L1(t=ph-1) [ph>0].
// Wh0+Wh1 register/AGPR-resident (128); Wx1 in 128KB LDS (swizzled, addresses
// hoisted to 8 pointers + imm offsets). One barrier/phase. X0 prefetch into
// dead acc via running pointers.
__global__ __launch_bounds__(512, 2) void lstm_f2(
    const float* __restrict__ X0, const ushort_t* __restrict__ Wh0,
    const ushort_t* __restrict__ Wx1, const ushort_t* __restrict__ Wh1,
    const float* __restrict__ lb, ushort_t* __restrict__ outB)
{
    extern __shared__ ushort_t smem[];
    // smem[0..8191]   : hbuf[4][2048]  (h0 p0, h0 p1, h1 p0, h1 p1)
    // smem[8192..]    : wxs 512x128 (16B-chunk swizzled)
    ushort_t* hbuf = smem;
    ushort_t* wxs  = smem + 8192;

    const int tid = threadIdx.x;
    const int wid = tid >> 6, lane = tid & 63;
    const int r0 = lane & 15, g = lane >> 4;
    const int sw = r0 & 7;
    const int bcb = blockIdx.x * 16;
    const float K1 = 1.44269504f, K2 = 2.88539008f;

    for (int i = tid; i < 8192; i += 512) hbuf[i] = 0;
    // stage Wx1 -> LDS: chunk c of col -> slot c^(col&7)
    for (int idx = tid; idx < 8192; idx += 512){
        int col = idx >> 4, c = idx & 15;
        *(bf16x8*)(wxs + col * 128 + ((c ^ (col & 7)) << 3)) =
            *(const bf16x8*)(Wx1 + col * 128 + c * 8);
    }

    // register-resident weights (B-fragments)
    bf16x8 wh0[4][4], wh1[4][4];
#pragma unroll
    for (int t4 = 0; t4 < 4; ++t4){
        const int cb = t4 * 128 + wid * 16;
#pragma unroll
        for (int kt = 0; kt < 4; ++kt){
            wh0[t4][kt] = *(const bf16x8*)(Wh0 + (cb + r0) * 128 + kt * 32 + g * 8);
            wh1[t4][kt] = *(const bf16x8*)(Wh1 + (cb + r0) * 128 + kt * 32 + g * 8);
        }
    }
    float b1v[4];
#pragma unroll
    for (int t4 = 0; t4 < 4; ++t4) b1v[t4] = lb[512 + t4 * 128 + wid * 16 + r0];

    // hoisted h-buffer read addresses (per kt); h1 = +8192B, parity = +-4096B imm
    const char* adr[4];
#pragma unroll
    for (int kt = 0; kt < 4; ++kt)
        adr[kt] = (const char*)hbuf + r0 * 256 + (((kt * 32 + g * 8) ^ (sw << 3)) << 1);
    // hoisted h-buffer write addresses (per q)
    char* wrq[4];
#pragma unroll
    for (int q = 0; q < 4; ++q){
        int row = g * 4 + q;
        wrq[q] = (char*)hbuf + row * 256 + (((wid * 16 + r0) ^ ((row & 7) << 3)) << 1);
    }
    // hoisted Wx1 LDS addresses: addr(t4,kt) = colb + (g^(sw&3))*16
    //   + [kt even: e | kt odd: 64-e] + (kt>=2 ? 128 : 0),  e=(sw>>2)*64
    const char* wxp[4][2];
    {
        const int e = (sw >> 2) * 64;
#pragma unroll
        for (int t4 = 0; t4 < 4; ++t4){
            const char* base = (const char*)wxs
                + (t4 * 128 + wid * 16 + r0) * 256 + ((g ^ (sw & 3)) * 16);
            wxp[t4][0] = base + e;
            wxp[t4][1] = base + (64 - e);
        }
    }
    // X0 running pointers (per q), starting at tn=1; t4 via +512B immediates
    const char* xp[4];
#pragma unroll
    for (int q = 0; q < 4; ++q)
        xp[q] = (const char*)(X0 + (bcb + g * 4 + q) * 4096 + wid * 16 + r0) + 2048;
    int tnn = 1;

    float c0[4] = {0,0,0,0}, c1[4] = {0,0,0,0};

    // acc preloaded with X0(t=0) slice (= Wx0@ctx + b0)
    f32x4 acc[4];
#pragma unroll
    for (int t4 = 0; t4 < 4; ++t4)
#pragma unroll
        for (int q = 0; q < 4; ++q)
            acc[t4][q] = *(const float*)(xp[q] - 2048 + t4 * 512);

    __syncthreads();

#pragma unroll 1
    for (int tt = 0; tt < 32; ++tt){
#pragma unroll
        for (int pp = 0; pp < 2; ++pp){
            const int ph = tt * 2 + pp;
            const int RDO = (pp ^ 1) * 4096;     // buffers written in phase ph-1
            const int WRO = pp * 4096;

            bf16x8 a0[4], ah[4];
#pragma unroll
            for (int kt = 0; kt < 4; ++kt){
                a0[kt] = *(const bf16x8*)(adr[kt] + RDO);          // h0(ph-1)
                ah[kt] = *(const bf16x8*)(adr[kt] + 8192 + RDO);   // h1(ph-2)
            }

            // ---- L0 MFMAs (t = ph): acc = X0(ph) + Wh0 @ h0(ph-1) ----
#pragma unroll
            for (int kt = 0; kt < 4; ++kt)
#pragma unroll
                for (int t4 = 0; t4 < 4; ++t4)
                    acc[t4] = __builtin_amdgcn_mfma_f32_16x16x32_bf16(a0[kt], wh0[t4][kt], acc[t4], 0, 0, 0);

            // ---- EW layer 0 -> h0[pp] ----
#pragma unroll
            for (int q = 0; q < 4; ++q){
                float iv = acc[0][q], fv = acc[1][q], gv = acc[2][q], ov = acc[3][q];
                float af = 1.f + __builtin_amdgcn_exp2f(-K1 * fv);
                float ai = 1.f + __builtin_amdgcn_exp2f(-K1 * iv);
                float bg = 1.f + __builtin_amdgcn_exp2f( K2 * gv);
                float cn = c0[q] * __builtin_amdgcn_rcpf(af)
                         + (bg - 2.f) * __builtin_amdgcn_rcpf(ai * bg);
                c0[q] = cn;
                float ao = 1.f + __builtin_amdgcn_exp2f(-K1 * ov);
                float bc = 1.f + __builtin_amdgcn_exp2f( K2 * cn);
                float hv = (bc - 2.f) * __builtin_amdgcn_rcpf(ao * bc);
                *(ushort_t*)(wrq[q] + WRO) = f2b(hv);
            }

            // ---- L1 (t = ph-1): acc = b1 + Wx1 @ h0(ph-1) + Wh1 @ h1(ph-2) ----
            if (ph > 0){
                f32x4 accB[4];
#pragma unroll
                for (int t4 = 0; t4 < 4; ++t4){
                    f32x4 tmp = {b1v[t4], b1v[t4], b1v[t4], b1v[t4]};
                    accB[t4] = tmp;
                }
#pragma unroll
                for (int kt = 0; kt < 4; ++kt)
#pragma unroll
                    for (int t4 = 0; t4 < 4; ++t4){
                        bf16x8 wx = *(const bf16x8*)(wxp[t4][kt & 1] + ((kt >> 1) << 7));
                        accB[t4] = __builtin_amdgcn_mfma_f32_16x16x32_bf16(a0[kt], wx,          accB[t4], 0, 0, 0);
                        accB[t4] = __builtin_amdgcn_mfma_f32_16x16x32_bf16(ah[kt], wh1[t4][kt], accB[t4], 0, 0, 0);
                    }
#pragma unroll
                for (int q = 0; q < 4; ++q){
                    float iv = accB[0][q], fv = accB[1][q], gv = accB[2][q], ov = accB[3][q];
                    float af = 1.f + __builtin_amdgcn_exp2f(-K1 * fv);
                    float ai = 1.f + __builtin_amdgcn_exp2f(-K1 * iv);
                    float bg = 1.f + __builtin_amdgcn_exp2f( K2 * gv);
                    float cn = c1[q] * __builtin_amdgcn_rcpf(af)
                             + (bg - 2.f) * __builtin_amdgcn_rcpf(ai * bg);
                    c1[q] = cn;
                    float ao = 1.f + __builtin_amdgcn_exp2f(-K1 * ov);
                    float bc = 1.f + __builtin_amdgcn_exp2f( K2 * cn);
                    float hv = (bc - 2.f) * __builtin_amdgcn_rcpf(ao * bc);
                    *(ushort_t*)(wrq[q] + 8192 + WRO) = f2b(hv);
                    if (ph >= 57){
                        int row = g * 4 + q;
                        outB[((bcb + row) * 8 + ((ph - 1) & 7)) * 128 + wid * 16 + r0] = f2b(hv);
                    }
                }
            }

            // ---- X0 prefetch for t = ph+1 into (now dead) acc ----
            if (ph < 63){
#pragma unroll
                for (int t4 = 0; t4 < 4; ++t4)
#pragma unroll
                    for (int q = 0; q < 4; ++q)
                        acc[t4][q] = *(const float*)(xp[q] + t4 * 512);
                long d = (tnn == 7) ? -14336L : 2048L;
                tnn = (tnn == 7) ? 0 : tnn + 1;
#pragma unroll
                for (int q = 0; q < 4; ++q) xp[q] += d;
            }
            __syncthreads();
        }
    }

    // ---- epilogue phase ph = 64: L1 only (t = 63), reads buffers of ph=63 ----
    {
        bf16x8 a0[4], ah[4];
#pragma unroll
        for (int kt = 0; kt < 4; ++kt){
            a0[kt] = *(const bf16x8*)(adr[kt] + 4096);
            ah[kt] = *(const bf16x8*)(adr[kt] + 8192 + 4096);
        }
        f32x4 acc2[4];
#pragma unroll
        for (int t4 = 0; t4 < 4; ++t4){
            f32x4 tmp = {b1v[t4], b1v[t4], b1v[t4], b1v[t4]};
            acc2[t4] = tmp;
        }
#pragma unroll
        for (int kt = 0; kt < 4; ++kt)
#pragma unroll
            for (int t4 = 0; t4 < 4; ++t4){
                bf16x8 wx = *(const bf16x8*)(wxp[t4][kt & 1] + ((kt >> 1) << 7));
                acc2[t4] = __builtin_amdgcn_mfma_f32_16x16x32_bf16(a0[kt], wx,          acc2[t4], 0, 0, 0);
                acc2[t4] = __builtin_amdgcn_mfma_f32_16x16x32_bf16(ah[kt], wh1[t4][kt], acc2[t4], 0, 0, 0);
            }
#pragma unroll
        for (int q = 0; q < 4; ++q){
            float iv = acc2[0][q], fv = acc2[1][q], gv = acc2[2][q], ov = acc2[3][q];
            float af = 1.f + __builtin_amdgcn_exp2f(-K1 * fv);
            float ai = 1.f + __builtin_amdgcn_exp2f(-K1 * iv);
            float bg = 1.f + __builtin_amdgcn_exp2f( K2 * gv);
            float cn = c1[q] * __builtin_amdgcn_rcpf(af)
                     + (bg - 2.f) * __builtin_amdgcn_rcpf(ai * bg);
            float ao = 1.f + __builtin_amdgcn_exp2f(-K1 * ov);
            float bc = 1.f + __builtin_amdgcn_exp2f( K2 * cn);
            float hv = (bc - 2.f) * __builtin_amdgcn_rcpf(ao * bc);
            int row = g * 4 + q;
            outB[((bcb + row) * 8 + 7) * 128 + wid * 16 + r0] = f2b(hv);
        }
    }
}

// ---------- fused tail: conv1d(SAME,K=3) -> ssm -> outp(+resid xn) -> proj ----------
__global__ __launch_bounds__(256) void tail_k(
    const ushort_t* __restrict__ ls, const ushort_t* __restrict__ cWk,
    const float* __restrict__ cbias, const ushort_t* __restrict__ sW,
    const float* __restrict__ sbias, const ushort_t* __restrict__ oW,
    const float* __restrict__ obias, const float* __restrict__ xnF,
    const ushort_t* __restrict__ pW, const float* __restrict__ pbias,
    float* __restrict__ out)
{
    __shared__ ushort_t bufA[8192];
    __shared__ ushort_t bufB[8192];
    const int lane = threadIdx.x & 63, wave = threadIdx.x >> 6;
    const int r0 = lane & 15, g = lane >> 4;
    const int rowbase = blockIdx.x * 64;
    const int lr0 = wave * 16;

    // ---- conv ----
    {
        const int n = r0 & 7;
        bf16x8 a[3][4];
#pragma unroll
        for (int k = 0; k < 3; ++k){
            bool valid = (n + k >= 1) && (n + k <= 8);
            const ushort_t* ap = ls + (rowbase + lr0 + r0 + k - 1) * 128 + g * 8;
#pragma unroll
            for (int kt = 0; kt < 4; ++kt){
                bf16x8 z = {0,0,0,0,0,0,0,0};
                a[k][kt] = valid ? *(const bf16x8*)(ap + kt * 32) : z;
            }
        }
#pragma unroll
        for (int nt = 0; nt < 8; ++nt){
            const int col = nt * 16 + r0;
            float bv = cbias[col];
            f32x4 acc = {bv, bv, bv, bv};
#pragma unroll
            for (int k = 0; k < 3; ++k)
#pragma unroll
                for (int kt = 0; kt < 4; ++kt)
                    acc = __builtin_amdgcn_mfma_f32_16x16x32_bf16(
                            a[k][kt], *(const bf16x8*)(cWk + k * 16384 + col * 128 + kt * 32 + g * 8),
                            acc, 0, 0, 0);
#pragma unroll
            for (int q = 0; q < 4; ++q){
                int row = lr0 + g * 4 + q;
                bufA[row * 128 + (col ^ ((row & 7) << 3))] = f2b(acc[q]);
            }
        }
    }
    __syncthreads();
    // ---- ssm: bufA -> bufB ----
    {
        bf16x8 a[4];
#pragma unroll
        for (int kt = 0; kt < 4; ++kt)
            a[kt] = *(const bf16x8*)(&bufA[(lr0 + r0) * 128 + ((kt * 32 + g * 8) ^ ((r0 & 7) << 3))]);
#pragma unroll
        for (int nt = 0; nt < 8; ++nt){
            const int col = nt * 16 + r0;
            float bv = sbias[col];
            f32x4 acc = {bv, bv, bv, bv};
#pragma unroll
            for (int kt = 0; kt < 4; ++kt)
                acc = __builtin_amdgcn_mfma_f32_16x16x32_bf16(
                        a[kt], *(const bf16x8*)(sW + col * 128 + kt * 32 + g * 8), acc, 0, 0, 0);
#pragma unroll
            for (int q = 0; q < 4; ++q){
                int row = lr0 + g * 4 + q;
                bufB[row * 128 + (col ^ ((row & 7) << 3))] = f2b(acc[q]);
            }
        }
    }
    __syncthreads();
    // ---- outp + resid: bufB -> bufA ----
    {
        bf16x8 a[4];
#pragma unroll
        for (int kt = 0; kt < 4; ++kt)
            a[kt] = *(const bf16x8*)(&bufB[(lr0 + r0) * 128 + ((kt * 32 + g * 8) ^ ((r0 & 7) << 3))]);
#pragma unroll
        for (int nt = 0; nt < 8; ++nt){
            const int col = nt * 16 + r0;
            float bv = obias[col];
            f32x4 acc = {bv, bv, bv, bv};
#pragma unroll
            for (int kt = 0; kt < 4; ++kt)
                acc = __builtin_amdgcn_mfma_f32_16x16x32_bf16(
                        a[kt], *(const bf16x8*)(oW + col * 128 + kt * 32 + g * 8), acc, 0, 0, 0);
#pragma unroll
            for (int q = 0; q < 4; ++q){
                int row = lr0 + g * 4 + q;
                float v = acc[q] + xnF[(rowbase + row) * 128 + col];
                bufA[row * 128 + (col ^ ((row & 7) << 3))] = f2b(v);
            }
        }
    }
    __syncthreads();
    // ---- proj: bufA -> out (96 cols, f32) ----
    {
        bf16x8 a[4];
#pragma unroll
        for (int kt = 0; kt < 4; ++kt)
            a[kt] = *(const bf16x8*)(&bufA[(lr0 + r0) * 128 + ((kt * 32 + g * 8) ^ ((r0 & 7) << 3))]);
#pragma unroll
        for (int nt = 0; nt < 6; ++nt){
            const int col = nt * 16 + r0;
            float bv = pbias[col];
            f32x4 acc = {bv, bv, bv, bv};
#pragma unroll
            for (int kt = 0; kt < 4; ++kt)
                acc = __builtin_amdgcn_mfma_f32_16x16x32_bf16(
                        a[kt], *(const bf16x8*)(pW + col * 128 + kt * 32 + g * 8), acc, 0, 0, 0);
#pragma unroll
            for (int q = 0; q < 4; ++q)
                out[(rowbase + lr0 + g * 4 + q) * 96 + col] = acc[q];
        }
    }
}

// ---------- launch ----------
extern "C" void kernel_launch(void* const* d_in, const int* in_sizes, int n_in,
                              void* d_out, int out_size, void* d_ws, size_t ws_size,
                              hipStream_t stream)
{
    const float* x   = (const float*)d_in[0];
    const float* eW  = (const float*)d_in[1];
    const float* eb  = (const float*)d_in[2];
    const float* lng = (const float*)d_in[3];
    const float* lnb = (const float*)d_in[4];
    const float* vW  = (const float*)d_in[9];
    const float* vb  = (const float*)d_in[10];
    const float* Wx  = (const float*)d_in[11];
    const float* Wh  = (const float*)d_in[12];
    const float* lb  = (const float*)d_in[13];
    const float* cW  = (const float*)d_in[14];
    const float* cb_ = (const float*)d_in[15];
    const float* sW  = (const float*)d_in[16];
    const float* sb  = (const float*)d_in[17];
    const float* oW  = (const float*)d_in[18];
    const float* ob  = (const float*)d_in[19];
    const float* pW  = (const float*)d_in[20];
    const float* pb  = (const float*)d_in[21];

    char* ws = (char*)d_ws;
    float*    xnF = (float*)   (ws + 0);          // 5376x128 f32   (2.75 MB)
    float*    X0F = (float*)   (ws + 5505024);    // 5376x512 f32   (11 MB)
    ushort_t* lsB = (ushort_t*)(ws + 16515072);   // lstm out bf16  (1.38 MB)
    ushort_t* wb  = (ushort_t*)(ws + 17891328);   // bf16 weights   (0.75 MB)

    hipFuncSetAttribute((const void*)lstm_f2,
                        hipFuncAttributeMaxDynamicSharedMemorySize, 147456);

    prep_k<<<dim3(256, 9), 256, 0, stream>>>(vW, Wx, Wh, cW, sW, oW, pW, wb);
    // fused embed+LN -> c0 -> X0 (single-wave blocks, no barriers)
    head_k<<<336, 64, 0, stream>>>(x, eW, eb, lng, lnb, wb + 0, vb, wb + 16384, lb,
                                   xnF, X0F);
    // fused layer-pipelined 2-layer recurrence (65 phases, one barrier each)
    lstm_f2<<<42, 512, 147456, stream>>>(X0F, wb + 81920, wb + 147456, wb + 212992,
                                         lb, lsB);
    tail_k<<<84, 256, 0, stream>>>(lsB, wb + 278528, cb_, wb + 327680, sb,
                                   wb + 344064, ob, xnF, wb + 360448, pb, (float*)d_out);
}